// Round 1
// baseline (802.036 us; speedup 1.0000x reference)
//
#include <hip/hip_runtime.h>
#include <math.h>

#define BB 8
#define CC 64
#define HH 128
#define WW 128
#define OO 64
#define HWHW (HH*WW)

// ---------------- Kernel 1: NCHW -> NHWC transpose of x ----------------
__global__ __launch_bounds__(256) void k_transpose(const float* __restrict__ x,
                                                   float* __restrict__ xt) {
  __shared__ float tile[64][65];
  int blk = blockIdx.x;            // 2048 blocks: 8 batches * 256 hw-chunks
  int b = blk >> 8;
  int hw0 = (blk & 255) << 6;      // 64 hw positions per block
  int lane = threadIdx.x & 63;
  int g = threadIdx.x >> 6;        // 0..3
  const float* xb = x + (size_t)b * CC * HWHW;
#pragma unroll
  for (int i = 0; i < 16; ++i) {
    int c = g + i * 4;
    tile[lane][c] = xb[c * HWHW + hw0 + lane];   // coalesced read along hw
  }
  __syncthreads();
  float* xtb = xt + (size_t)b * HWHW * CC;
#pragma unroll
  for (int j = 0; j < 16; ++j) {
    int hwl = g + j * 4;
    xtb[(size_t)(hw0 + hwl) * 64 + lane] = tile[hwl][lane];  // coalesced along c
  }
}

// ---------------- Kernel 2: reorder w_dcn [O][C*9] -> w_r [kc][O] ----------------
__global__ __launch_bounds__(256) void k_wreorder(const float* __restrict__ w,
                                                  float* __restrict__ wr) {
  int i = blockIdx.x * 256 + threadIdx.x;  // 36864 elements
  int o = i / 576;
  int kc = i % 576;
  wr[kc * 64 + o] = w[i];
}

// ---------------- Kernel 3: fused offset+mask 3x3 conv ----------------
// 27 output channels (18 offset raw, 9 mask sigmoid). 2 pixels per thread.
__global__ __launch_bounds__(256) void k_convom(const float* __restrict__ x,
                                                const float* __restrict__ w_off,
                                                const float* __restrict__ b_off,
                                                const float* __restrict__ w_mask,
                                                const float* __restrict__ b_mask,
                                                float* __restrict__ off_out,
                                                float* __restrict__ mask_out) {
  __shared__ float wlds[27 * 576];   // 62,208 B
  for (int i = threadIdx.x; i < 18 * 576; i += 256) wlds[i] = w_off[i];
  for (int i = threadIdx.x; i < 9 * 576; i += 256) wlds[18 * 576 + i] = w_mask[i];
  __syncthreads();

  int t = blockIdx.x * 256 + threadIdx.x;  // 65536 threads, 2 px each
  int pix = t * 2;
  int b = pix / HWHW;
  int hw = pix % HWHW;
  int y = hw / WW;
  int x0 = hw % WW;                        // even, pair stays in row

  float acc[27][2];
#pragma unroll
  for (int ch = 0; ch < 27; ++ch) { acc[ch][0] = 0.f; acc[ch][1] = 0.f; }

  const float* xb = x + (size_t)b * CC * HWHW;
  for (int c = 0; c < CC; ++c) {
    float xv[3][4];
#pragma unroll
    for (int r = 0; r < 3; ++r) {
      int yy = y + r - 1;
      bool yok = ((unsigned)yy < (unsigned)HH);
      const float* rowp = xb + c * HWHW + yy * WW;
#pragma unroll
      for (int q = 0; q < 4; ++q) {
        int xx = x0 + q - 1;
        bool ok = yok && ((unsigned)xx < (unsigned)WW);
        xv[r][q] = ok ? rowp[xx] : 0.f;
      }
    }
    const float* wc = &wlds[c * 9];
#pragma unroll
    for (int ch = 0; ch < 27; ++ch) {
      const float* wp = wc + ch * 576;
#pragma unroll
      for (int r = 0; r < 3; ++r) {
#pragma unroll
        for (int q = 0; q < 3; ++q) {
          float wv = wp[r * 3 + q];
          acc[ch][0] += xv[r][q] * wv;
          acc[ch][1] += xv[r][q + 1] * wv;
        }
      }
    }
  }

  int base_off = b * 18 * HWHW + y * WW + x0;
#pragma unroll
  for (int ch = 0; ch < 18; ++ch) {
    float bb = b_off[ch];
    off_out[base_off + ch * HWHW] = acc[ch][0] + bb;
    off_out[base_off + ch * HWHW + 1] = acc[ch][1] + bb;
  }
  int base_m = b * 9 * HWHW + y * WW + x0;
#pragma unroll
  for (int ch = 0; ch < 9; ++ch) {
    float bb = b_mask[ch];
    float v0 = acc[18 + ch][0] + bb;
    float v1 = acc[18 + ch][1] + bb;
    mask_out[base_m + ch * HWHW] = 1.f / (1.f + expf(-v0));
    mask_out[base_m + ch * HWHW + 1] = 1.f / (1.f + expf(-v1));
  }
}

// ---------------- Kernel 4: deformable conv ----------------
// Block = 256 thr (4 waves), 16 consecutive-x pixels.
// Phase 1: wave-per-4-pixels, lane=channel, bilinear gather from NHWC -> LDS cols.
// Phase 2: thread=(pixel p, 4 out-channels), K=576 matvec with w_r[kc][o].
#define COLS_STRIDE 580
__global__ __launch_bounds__(256) void k_deform(const float* __restrict__ xt,
                                                const float* __restrict__ off,
                                                const float* __restrict__ msk,
                                                const float* __restrict__ wr,
                                                float* __restrict__ out) {
  __shared__ __align__(16) float cols[16 * COLS_STRIDE];  // 37,120 B
  int blk = blockIdx.x;          // 8192 blocks
  int pix0 = blk * 16;
  int b = pix0 / HWHW;
  int hw0 = pix0 % HWHW;
  int y = hw0 / WW;
  int x0 = hw0 % WW;             // 16 consecutive x in one row
  int wave = threadIdx.x >> 6;
  int lane = threadIdx.x & 63;   // = input channel c
  const float* xb = xt + (size_t)b * HWHW * 64;

#pragma unroll
  for (int pp = 0; pp < 4; ++pp) {
    int p = wave * 4 + pp;
    int xx = x0 + p;
    const float* offp = off + b * 18 * HWHW + y * WW + xx;
    const float* mp = msk + b * 9 * HWHW + y * WW + xx;
#pragma unroll
    for (int k = 0; k < 9; ++k) {
      float dy = offp[(2 * k) * HWHW];
      float dx = offp[(2 * k + 1) * HWHW];
      float m = mp[k * HWHW];
      float py = (float)(y + k / 3 - 1) + dy;
      float px = (float)(xx + k % 3 - 1) + dx;
      float fy = floorf(py);
      float fx = floorf(px);
      int y0i = (int)fy;
      int x0i = (int)fx;
      float wy1 = py - fy;
      float wx1 = px - fx;
      float v00 = 0.f, v01 = 0.f, v10 = 0.f, v11 = 0.f;
      if ((unsigned)y0i < (unsigned)HH) {
        const float* rp = xb + (size_t)(y0i * WW) * 64;
        if ((unsigned)x0i < (unsigned)WW) v00 = rp[x0i * 64 + lane];
        if ((unsigned)(x0i + 1) < (unsigned)WW) v01 = rp[(x0i + 1) * 64 + lane];
      }
      if ((unsigned)(y0i + 1) < (unsigned)HH) {
        const float* rp = xb + (size_t)((y0i + 1) * WW) * 64;
        if ((unsigned)x0i < (unsigned)WW) v10 = rp[x0i * 64 + lane];
        if ((unsigned)(x0i + 1) < (unsigned)WW) v11 = rp[(x0i + 1) * 64 + lane];
      }
      float val = ((v00 * (1.f - wx1) + v01 * wx1) * (1.f - wy1) +
                   (v10 * (1.f - wx1) + v11 * wx1) * wy1) * m;
      cols[p * COLS_STRIDE + lane * 9 + k] = val;
    }
  }
  __syncthreads();

  // Phase 2
  int p = threadIdx.x & 15;
  int og = threadIdx.x >> 4;     // 0..15 -> out channels og*4..og*4+3
  float acc0 = 0.f, acc1 = 0.f, acc2 = 0.f, acc3 = 0.f;
  const float* colp = &cols[p * COLS_STRIDE];
  for (int kc = 0; kc < 576; kc += 4) {
    float4 cv = *(const float4*)(colp + kc);
    float cva[4] = {cv.x, cv.y, cv.z, cv.w};
#pragma unroll
    for (int j = 0; j < 4; ++j) {
      float4 wv = *(const float4*)(wr + (kc + j) * 64 + og * 4);
      acc0 += cva[j] * wv.x;
      acc1 += cva[j] * wv.y;
      acc2 += cva[j] * wv.z;
      acc3 += cva[j] * wv.w;
    }
  }
  int xx = x0 + p;
  size_t obase = (size_t)(b * 64 + og * 4) * HWHW + y * WW + xx;
  out[obase] = acc0;
  out[obase + HWHW] = acc1;
  out[obase + 2 * HWHW] = acc2;
  out[obase + 3 * HWHW] = acc3;
}

extern "C" void kernel_launch(void* const* d_in, const int* in_sizes, int n_in,
                              void* d_out, int out_size, void* d_ws, size_t ws_size,
                              hipStream_t stream) {
  const float* x = (const float*)d_in[0];
  const float* w_off = (const float*)d_in[1];
  const float* b_off = (const float*)d_in[2];
  const float* w_mask = (const float*)d_in[3];
  const float* b_mask = (const float*)d_in[4];
  const float* w_dcn = (const float*)d_in[5];
  float* out = (float*)d_out;

  char* ws = (char*)d_ws;
  float* xt = (float*)ws;                                  // 33,554,432 B
  float* off = (float*)(ws + 33554432);                    //  9,437,184 B
  float* msk = (float*)(ws + 33554432 + 9437184);          //  4,718,592 B
  float* wr = (float*)(ws + 33554432 + 9437184 + 4718592); //    147,456 B

  hipLaunchKernelGGL(k_transpose, dim3(2048), dim3(256), 0, stream, x, xt);
  hipLaunchKernelGGL(k_wreorder, dim3(144), dim3(256), 0, stream, w_dcn, wr);
  hipLaunchKernelGGL(k_convom, dim3(256), dim3(256), 0, stream, x, w_off, b_off,
                     w_mask, b_mask, off, msk);
  hipLaunchKernelGGL(k_deform, dim3(8192), dim3(256), 0, stream, xt, off, msk, wr, out);
}